// Round 16
// baseline (48.578 us; speedup 1.0000x reference)
//
#include <hip/hip_runtime.h>

#define DIM   64
#define NROWS 65536
#define NCODE 1024
#define RPB   64
#define NBLK  (NROWS / RPB)   // 1024 blocks x 512 thr (8 waves) -> 4 blk/CU, 32 waves/CU

typedef float    f32x4 __attribute__((ext_vector_type(4)));
typedef _Float16 f16x8 __attribute__((ext_vector_type(8)));

union U4H { uint4 u; f16x8 h; };

// fp32 = h + r, h = RNE fp16; r exact (Sterbenz); l = RNE fp16 of r.
__device__ __forceinline__ void split2(float f, unsigned short& hb,
                                       unsigned short& lb) {
  _Float16 h = (_Float16)f;
  float r = f - (float)h;
  _Float16 lo = (_Float16)r;
  hb = __builtin_bit_cast(unsigned short, h);
  lb = __builtin_bit_cast(unsigned short, lo);
}
__device__ __forceinline__ uint4 pack8(const unsigned short* p) {
  return make_uint4((unsigned)p[0] | ((unsigned)p[1] << 16),
                    (unsigned)p[2] | ((unsigned)p[3] << 16),
                    (unsigned)p[4] | ((unsigned)p[5] << 16),
                    (unsigned)p[6] | ((unsigned)p[7] << 16));
}

// ---- pre-pass: e -> fp16 (h,l) B-fragments + e2/2; also zeroes loss ----
// tile gt (16 codes): 4 frags [kh0_h, kh0_l, kh1_h, kh1_l] x 512 shorts,
// each frag lane-linear: lane l owns shorts [l*8, l*8+8).
__global__ __launch_bounds__(256) void vq_esplit(const float* __restrict__ e,
                                                 unsigned short* __restrict__ eB,
                                                 float* __restrict__ e2h,
                                                 float* __restrict__ loss) {
  const int c = blockIdx.x * 256 + threadIdx.x;   // code 0..1023
  if (c == 0) *loss = 0.f;                        // stream-ordered before vq_main
  const int gt = c >> 4, cl = c & 15;
  float s = 0.f;
  #pragma unroll
  for (int kh = 0; kh < 2; ++kh) {
    #pragma unroll
    for (int g = 0; g < 4; ++g) {
      const float* ep = e + (size_t)c * DIM + kh * 32 + g * 8;
      float4 v0 = *(const float4*)ep;
      float4 v1 = *(const float4*)(ep + 4);
      float f[8] = {v0.x, v0.y, v0.z, v0.w, v1.x, v1.y, v1.z, v1.w};
      unsigned short hb[8], lb[8];
      #pragma unroll
      for (int j = 0; j < 8; ++j) {
        split2(f[j], hb[j], lb[j]);
        s = fmaf(f[j], f[j], s);
      }
      const size_t pos = (size_t)((g << 4) | cl) * 8;
      const size_t tb = (size_t)gt * 2048;
      *(uint4*)(eB + tb + (kh * 2 + 0) * 512 + pos) = pack8(hb);
      *(uint4*)(eB + tb + (kh * 2 + 1) * 512 + pos) = pack8(lb);
    }
  }
  e2h[c] = 0.5f * s;
}

// one 16B-per-lane async global->LDS copy (1 KB per wave-instruction)
__device__ __forceinline__ void load_lds16(const void* gsrc, void* ldst) {
  __builtin_amdgcn_global_load_lds(
      (const __attribute__((address_space(1))) unsigned int*)
          (unsigned long long)gsrc,
      (__attribute__((address_space(3))) unsigned int*)
          (unsigned long long)ldst,
      16, 0, 0);
}

// ---- main: 64 rows/block, 8 waves = 4 row-groups x 2 code-halves.
// Wave (rg,h): 16 rows x 512 codes, 32 tile-steps from its half's 4-slot
// ring (depth-3 staging). 8192 waves total -> 32 waves/CU. ----
__global__ __launch_bounds__(512, 8) void vq_main(
    const float* __restrict__ x,
    const float* __restrict__ e,
    const unsigned short* __restrict__ eB,
    const float* __restrict__ e2h,
    float* __restrict__ out,
    float* __restrict__ loss)
{
  __shared__ __align__(16) unsigned short ring[2][4][2048]; // 2 halves x 16 KB
  __shared__ __align__(16) float e2L[NCODE];                // 4 KB
  __shared__ float bestL[8][16];
  __shared__ int   kL[8][16];
  __shared__ int   kFin[RPB];
  __shared__ float x2P[4];

  const int t   = threadIdx.x;
  const int l   = t & 63;
  const int wv  = t >> 6;                    // 0..7
  const int h   = wv >> 2;                   // code half (0: tiles 0-31, 1: 32-63)
  const int rg  = wv & 3;                    // row group
  const int col = l & 15;
  const int g   = l >> 4;
  const int B0  = blockIdx.x * RPB;
  const int R0  = B0 + rg * 16;              // this wave's 16 rows
  const int ph  = (blockIdx.x * 7) & 31;     // phase: decorrelate L2 streams

  // ---- x loads first (oldest vmem; consumed in prologue) ----
  float4 xv[4];
  #pragma unroll
  for (int kh = 0; kh < 2; ++kh) {
    const float* xp = x + (size_t)(R0 + col) * DIM + kh * 32 + g * 8;
    xv[kh * 2 + 0] = *(const float4*)xp;
    xv[kh * 2 + 1] = *(const float4*)(xp + 4);
  }

  // ---- async stages: e2 (waves 4-7 duplicate waves 0-3: uniform vmcnt,
  // identical data -> benign) + tiles 0..2 (depth 3) ----
  load_lds16(e2h + rg * 256 + l * 4, e2L + rg * 256);

#define STAGE(M)                                                         \
  do {                                                                   \
    const int pt_ = h * 32 + ((ph + (M)) & 31);                          \
    load_lds16(eB + (size_t)pt_ * 2048 + rg * 512 + (size_t)l * 8,       \
               &ring[h][(M) & 3][0] + rg * 512);                         \
  } while (0)

  STAGE(0); STAGE(1); STAGE(2);

  // ---- split x -> fp16 (h,l) A-frags + Sum(x^2) over this wave's 16 rows ----
  f16x8 a[2][2];     // [k-half][h/l]
  float x2p = 0.f;
  #pragma unroll
  for (int kh = 0; kh < 2; ++kh) {
    float4 v0 = xv[kh * 2], v1 = xv[kh * 2 + 1];
    float f[8] = {v0.x, v0.y, v0.z, v0.w, v1.x, v1.y, v1.z, v1.w};
    unsigned short hb[8], lb[8];
    #pragma unroll
    for (int j = 0; j < 8; ++j) {
      split2(f[j], hb[j], lb[j]);
      x2p = fmaf(f[j], f[j], x2p);
    }
    U4H uh; uh.u = pack8(hb); a[kh][0] = uh.h;
    U4H ul; ul.u = pack8(lb); a[kh][1] = ul.h;
  }
  #pragma unroll
  for (int off = 1; off < 64; off <<= 1) x2p += __shfl_xor(x2p, off, 64);

  float bestS[4];
  int   bestK[4];
  #pragma unroll
  for (int r = 0; r < 4; ++r) { bestS[r] = -3.402823466e38f; bestK[r] = 0x7FFFFFFF; }

#define VMWAIT2                                                \
  do {                                                         \
    asm volatile("s_waitcnt vmcnt(2)" ::: "memory");           \
    __builtin_amdgcn_sched_barrier(0);                         \
  } while (0)

  // Steady state: 3 stage-loads outstanding; VMWAIT(2) -> own chunk of tile m
  // landed (in-order retirement); barrier -> all 4 chunk-waves of this half
  // landed -> tile complete. STAGE(m+3) writes slot (m+3)&3 = slot of tile
  // m-1, whose reads completed before the barrier just passed -> race-free.
  // Wrap-staging (&31) keeps vmcnt uniform through the tail.
  #pragma unroll 4
  for (int m = 0; m < 32; ++m) {
    VMWAIT2;
    __builtin_amdgcn_s_barrier();
    STAGE(m + 3);
    const int ht  = h * 32 + ((ph + m) & 31);
    const int kk0 = ht * 16 + col;
    const unsigned short* sl = &ring[h][m & 3][0];
    uint4 u0 = *(const uint4*)(sl + 0 * 512 + l * 8);
    uint4 u1 = *(const uint4*)(sl + 1 * 512 + l * 8);
    uint4 u2 = *(const uint4*)(sl + 2 * 512 + l * 8);
    uint4 u3 = *(const uint4*)(sl + 3 * 512 + l * 8);
    const float ne2 = -e2L[kk0];
    U4H q0, q1, q2, q3; q0.u = u0; q1.u = u1; q2.u = u2; q3.u = u3;
    f32x4 c0 = {ne2, ne2, ne2, ne2};
    f32x4 c1 = {0.f, 0.f, 0.f, 0.f};
    c0 = __builtin_amdgcn_mfma_f32_16x16x32_f16(a[0][0], q0.h, c0, 0, 0, 0);
    c1 = __builtin_amdgcn_mfma_f32_16x16x32_f16(a[1][0], q2.h, c1, 0, 0, 0);
    c0 = __builtin_amdgcn_mfma_f32_16x16x32_f16(a[0][1], q0.h, c0, 0, 0, 0);
    c1 = __builtin_amdgcn_mfma_f32_16x16x32_f16(a[1][1], q2.h, c1, 0, 0, 0);
    c0 = __builtin_amdgcn_mfma_f32_16x16x32_f16(a[0][0], q1.h, c0, 0, 0, 0);
    c1 = __builtin_amdgcn_mfma_f32_16x16x32_f16(a[1][0], q3.h, c1, 0, 0, 0);
    #pragma unroll
    for (int r = 0; r < 4; ++r) {
      float sv = c0[r] + c1[r];
      bool take = (sv > bestS[r]) || (sv == bestS[r] && kk0 < bestK[r]);
      if (take) { bestS[r] = sv; bestK[r] = kk0; }
    }
  }

  // ---- intra-wave argmax(S') merge over the 16 code-columns ----
  #pragma unroll
  for (int off = 1; off <= 8; off <<= 1) {
    #pragma unroll
    for (int r = 0; r < 4; ++r) {
      float sp = __shfl_xor(bestS[r], off, 64);
      int   kp = __shfl_xor(bestK[r], off, 64);
      if (sp > bestS[r] || (sp == bestS[r] && kp < bestK[r])) {
        bestS[r] = sp; bestK[r] = kp;
      }
    }
  }

  // col==0 lanes (g=0..3) hold this wave's minima for rows R0 + g*4 + r
  if (col == 0) {
    #pragma unroll
    for (int r = 0; r < 4; ++r) {
      bestL[wv][g * 4 + r] = bestS[r];
      kL[wv][g * 4 + r]    = bestK[r];
    }
  }
  if (h == 0 && l == 0) x2P[rg] = x2p;   // each row's x2 counted once
  __syncthreads();

  // ---- cross-half merge (half 0 = lower codes -> strict > keeps ties) ----
  if (t < RPB) {
    const int rq = t >> 4, ri = t & 15;
    float s0 = bestL[rq][ri];     int k0 = kL[rq][ri];
    float s1 = bestL[4 + rq][ri]; int k1 = kL[4 + rq][ri];
    if (s1 > s0) { s0 = s1; k0 = k1; }
    kFin[t] = k0;
    float v = s0;                        // t<64 = wave 0: shuffle-reduce
    #pragma unroll
    for (int off = 1; off < 64; off <<= 1) v += __shfl_xor(v, off, 64);
    if (t == 0) {
      float x2tot = (x2P[0] + x2P[1]) + (x2P[2] + x2P[3]);
      atomicAdd(loss, fmaf(-2.f, v, x2tot) * (1.25f / (float)((size_t)NROWS * DIM)));
    }
  }
  __syncthreads();

  // ---- cooperative gather-write: 8 threads/row, 8 floats each ----
  {
    const int row = t >> 3, seg = t & 7;
    const int bk = kFin[row];
    const float4* src = (const float4*)(e + (size_t)bk * DIM + seg * 8);
    float4* dst = (float4*)(out + (size_t)(B0 + row) * DIM + seg * 8);
    dst[0] = src[0];
    dst[1] = src[1];
  }
}

extern "C" void kernel_launch(void* const* d_in, const int* in_sizes, int n_in,
                              void* d_out, int out_size, void* d_ws, size_t ws_size,
                              hipStream_t stream) {
  const float* x = (const float*)d_in[0];   // [65536, 64]
  const float* e = (const float*)d_in[1];   // [1024, 64]
  float* out  = (float*)d_out;              // quantized_st [65536*64] + loss [1]
  float* loss = out + (size_t)NROWS * DIM;

  unsigned short* eB = (unsigned short*)d_ws;            // 64 tiles * 4 KB = 256 KB
  float* e2h = (float*)((char*)d_ws + 64 * 2048 * 2);    // 4 KB

  vq_esplit<<<NCODE / 256, 256, 0, stream>>>(e, eB, e2h, loss);
  vq_main  <<<NBLK, 512, 0, stream>>>(x, e, eB, e2h, out, loss);
}